// Round 6
// baseline (340.121 us; speedup 1.0000x reference)
//
#include <hip/hip_runtime.h>
#include <hip/hip_bf16.h>

// Problem constants (fixed by the reference)
#define CS     128
#define EDIM   256
#define NBATCH 2
#define TLEN   8192
#define NCHUNK 64
#define LEXT   1024
#define KSEL   7

typedef __attribute__((ext_vector_type(8))) short   short8;   // 8 bf16 = 4 VGPR (MFMA A/B frag)
typedef __attribute__((ext_vector_type(4))) float   floatx4;  // MFMA C/D frag

__device__ inline short bf16_of(float f) {
    __hip_bfloat16 h = __float2bfloat16(f);
    return *(short*)&h;
}
__device__ inline float f_of_bf16(short s) {
    __hip_bfloat16 h = *(__hip_bfloat16*)&s;
    return __bfloat162float(h);
}

// async global->LDS, 16B per lane; LDS dest = wave-uniform base + lane*16
__device__ inline void gl_lds16(const void* g, void* l) {
    __builtin_amdgcn_global_load_lds(
        (const __attribute__((address_space(1))) unsigned int*)g,
        (__attribute__((address_space(3))) unsigned int*)l, 16, 0, 0);
}

// ---------------------------------------------------------------------------
// Stage A1: normalize rows, split to bf16 hi/lo (for scores). One wave/row.
// ---------------------------------------------------------------------------
__global__ __launch_bounds__(256) void normsplit_kernel(const float* __restrict__ x,
                                                        short* __restrict__ cn_hi,
                                                        short* __restrict__ cn_lo) {
    int row  = blockIdx.x * 4 + (threadIdx.x >> 6);
    int lane = threadIdx.x & 63;
    const float4 v = ((const float4*)(x + (size_t)row * EDIM))[lane];
    float s = v.x * v.x + v.y * v.y + v.z * v.z + v.w * v.w;
#pragma unroll
    for (int off = 1; off < 64; off <<= 1) s += __shfl_xor(s, off);
    float r = 1.0f / (sqrtf(s) + 1e-6f);

    float c[4] = {v.x * r, v.y * r, v.z * r, v.w * r};
    short hs[4], ls[4];
#pragma unroll
    for (int q = 0; q < 4; ++q) {
        hs[q] = bf16_of(c[q]);
        ls[q] = bf16_of(c[q] - f_of_bf16(hs[q]));
    }
    size_t o = (size_t)row * EDIM + lane * 4;
    *(short4*)(cn_hi + o) = make_short4(hs[0], hs[1], hs[2], hs[3]);
    *(short4*)(cn_lo + o) = make_short4(ls[0], ls[1], ls[2], ls[3]);
}

// ---------------------------------------------------------------------------
// Stage A2: split down_proj to bf16 hi/lo (131072 elems, float4/thread)
// ---------------------------------------------------------------------------
__global__ __launch_bounds__(256) void dp_split_kernel(const float* __restrict__ dp,
                                                       short* __restrict__ dph,
                                                       short* __restrict__ dpl) {
    int idx = (blockIdx.x * 256 + threadIdx.x) * 4;
    float4 v = *(const float4*)(dp + idx);
    float c[4] = {v.x, v.y, v.z, v.w};
    short hs[4], ls[4];
#pragma unroll
    for (int q = 0; q < 4; ++q) {
        hs[q] = bf16_of(c[q]);
        ls[q] = bf16_of(c[q] - f_of_bf16(hs[q]));
    }
    *(short4*)(dph + idx) = make_short4(hs[0], hs[1], hs[2], hs[3]);
    *(short4*)(dpl + idx) = make_short4(ls[0], ls[1], ls[2], ls[3]);
}

// ---------------------------------------------------------------------------
// Stage A3: transpose x to [b][e][t] + split bf16 hi/lo (for out B-operand)
// ---------------------------------------------------------------------------
__global__ __launch_bounds__(256) void xt_split_kernel(const float* __restrict__ x,
                                                       short* __restrict__ xth,
                                                       short* __restrict__ xtl) {
    __shared__ float tile[64][68];
    const int e0 = blockIdx.x * 64, t0 = blockIdx.y * 64, b = blockIdx.z;
    const int tid = threadIdx.x;
    const int cr = tid >> 4, cc = (tid & 15) * 4;
#pragma unroll
    for (int p = 0; p < 4; ++p) {
        int r = cr + p * 16;
        float4 v = *(const float4*)(x + ((size_t)(b * TLEN + t0 + r)) * EDIM + e0 + cc);
        *(float4*)&tile[r][cc] = v;
    }
    __syncthreads();
    const int e = tid >> 2, toff = (tid & 3) * 16;
    short hs[16], ls[16];
#pragma unroll
    for (int q = 0; q < 16; ++q) {
        float f = tile[toff + q][e];
        hs[q] = bf16_of(f);
        ls[q] = bf16_of(f - f_of_bf16(hs[q]));
    }
    size_t o = ((size_t)(b * EDIM + e0 + e)) * TLEN + t0 + toff;
#pragma unroll
    for (int q4 = 0; q4 < 4; ++q4) {
        *(short4*)(xth + o + q4 * 4) = make_short4(hs[q4*4], hs[q4*4+1], hs[q4*4+2], hs[q4*4+3]);
        *(short4*)(xtl + o + q4 * 4) = make_short4(ls[q4*4], ls[q4*4+1], ls[q4*4+2], ls[q4*4+3]);
    }
}

// ---------------------------------------------------------------------------
// Stage B v3: 2x1 i-superchunk split-bf16 MFMA cosine scores.
// Block p -> (I, j): rows = chunks {2I, 2I+1} (256 rows), cols = chunk j
// (j in [0, 2I]); emits score(2I,j) if j<2I and score(2I+1,j) always.
// Blocks/batch = sum(2I+1) = 1024; grid 2048; 512 thr, 2 blocks/CU
// (launch_bounds(512,4)) -> 512 resident -> exactly 4.0 grid-waves (no tail).
// A (both i-chunks, hi+lo) LDS-staged double-buffered (2x32KB);
// B (j-chunk) register-direct global loads, issued BEFORE next-kstep
// gl_lds stage so the vmcnt wait for B leaves the stage in flight.
// Per block-kstep: 384 MFMA vs 32 gl_lds (2x round-3 MFMA:barrier ratio).
// Numerics: identical 3-pass/ks-order as round 3 -> sims bit-identical.
// ---------------------------------------------------------------------------
__global__ __launch_bounds__(512, 4) void scores_mfma(const short* __restrict__ cn_hi,
                                                      const short* __restrict__ cn_lo,
                                                      float* __restrict__ scores) {
    __shared__ short  As[2][4 * 4096];   // [buf][m: chunk(2)xhl(2)][128r * 32k] = 64 KB
    __shared__ float  redbuf[2][256];
    __shared__ double sred[4];

    const int p = blockIdx.x, b = blockIdx.y;
    int I = (int)sqrtf((float)p);
    while ((I + 1) * (I + 1) <= p) ++I;
    while (I * I > p) --I;
    const int j = p - I * I;          // 0 .. 2I
    const int i0 = 2 * I, i1 = 2 * I + 1;

    const int tid  = threadIdx.x;
    const int w    = tid >> 6, lane = tid & 63;
    const int wr   = w >> 1, wc = w & 1;        // wr 0..3 (64-row group), wc 0..1 (64-col half)
    const int quad = lane >> 4, l15 = lane & 15;
    const int rr   = lane >> 2, c16 = (lane & 3) * 8;

    // staging role: matrix m = w>>1 (chunk = m>>1, hl = m&1), row-half = w&1
    const int sm = w >> 1, shalf = w & 1;
    const short* sarr  = (sm & 1) ? cn_lo : cn_hi;
    const short* sbase = sarr + ((size_t)b * TLEN + (size_t)((sm >> 1) ? i1 : i0) * CS + shalf * 64) * EDIM + c16;
    const int sdoff = sm * 4096 + shalf * 64 * 32;   // short offset within As[buf]

    // B source rows (j-chunk)
    const short* bhbase = cn_hi + ((size_t)b * TLEN + (size_t)j * CS) * EDIM;
    const short* blbase = cn_lo + ((size_t)b * TLEN + (size_t)j * CS) * EDIM;

    // A compute-read base: chunk ci = wr>>1, row-in-tile = (wr&1)*64 + rt*16 + l15
    const int ahoff = (wr >> 1) * 2 * 4096 + ((wr & 1) * 64) * 32;
    const int aloff = ahoff + 4096;

    floatx4 acc[4][4];
#pragma unroll
    for (int rt = 0; rt < 4; ++rt)
#pragma unroll
        for (int ct = 0; ct < 4; ++ct) acc[rt][ct] = (floatx4){0.f, 0.f, 0.f, 0.f};

    // prologue: stage ks=0 into buf 0
#pragma unroll
    for (int t = 0; t < 4; ++t)
        gl_lds16(sbase + (size_t)(t * 16 + rr) * EDIM, &As[0][0] + sdoff + t * 512);
    __syncthreads();

    int buf = 0;
#pragma unroll
    for (int ks = 0; ks < 8; ++ks) {
        // B register loads for THIS kstep (issued first: older than the stage,
        // so the compiler's vmcnt wait for B completion keeps the stage in flight)
        short8 bh[4], bl[4];
#pragma unroll
        for (int ct = 0; ct < 4; ++ct) {
            size_t off = (size_t)(wc * 64 + ct * 16 + l15) * EDIM + ks * 32 + quad * 8;
            bh[ct] = *(const short8*)(bhbase + off);
            bl[ct] = *(const short8*)(blbase + off);
        }
        // stage next kstep into the other buffer (overlaps compute below)
        if (ks < 7) {
#pragma unroll
            for (int t = 0; t < 4; ++t)
                gl_lds16(sbase + (size_t)(t * 16 + rr) * EDIM + (ks + 1) * 32,
                         &As[buf ^ 1][0] + sdoff + t * 512);
        }
        // compute on current buffer
#pragma unroll
        for (int rt = 0; rt < 4; ++rt) {
            int ro = (rt * 16 + l15) * 32 + quad * 8;
            short8 ah = *(const short8*)&As[buf][ahoff + ro];
            short8 al = *(const short8*)&As[buf][aloff + ro];
#pragma unroll
            for (int ct = 0; ct < 4; ++ct) {
                acc[rt][ct] = __builtin_amdgcn_mfma_f32_16x16x32_bf16(ah, bh[ct], acc[rt][ct], 0, 0, 0);
                acc[rt][ct] = __builtin_amdgcn_mfma_f32_16x16x32_bf16(ah, bl[ct], acc[rt][ct], 0, 0, 0);
                acc[rt][ct] = __builtin_amdgcn_mfma_f32_16x16x32_bf16(al, bh[ct], acc[rt][ct], 0, 0, 0);
            }
        }
        __syncthreads();   // next buf staged; current buf free for overwrite
        buf ^= 1;
    }

    // epilogue: D[row = wr*64 + rt*16 + quad*4 + reg][col = wc*64 + ct*16 + l15]
    // rowmax over this wave's 64 cols -> redbuf[wc][row]
#pragma unroll
    for (int rt = 0; rt < 4; ++rt) {
        float m[4];
#pragma unroll
        for (int reg = 0; reg < 4; ++reg) {
            float mm = acc[rt][0][reg];
#pragma unroll
            for (int ct = 1; ct < 4; ++ct) mm = fmaxf(mm, acc[rt][ct][reg]);
            m[reg] = mm;
        }
#pragma unroll
        for (int off = 1; off < 16; off <<= 1)
#pragma unroll
            for (int reg = 0; reg < 4; ++reg) m[reg] = fmaxf(m[reg], __shfl_xor(m[reg], off));
        if (l15 == 0) {
#pragma unroll
            for (int reg = 0; reg < 4; ++reg)
                redbuf[wc][wr * 64 + rt * 16 + quad * 4 + reg] = m[reg];
        }
    }
    __syncthreads();

    // rows 0..127 -> score(i0, j); rows 128..255 -> score(i1, j)
    if (tid < 256) {
        double part = (double)fmaxf(redbuf[0][tid], redbuf[1][tid]);
#pragma unroll
        for (int off = 1; off < 64; off <<= 1) part += __shfl_xor(part, off);
        if (lane == 0) sred[w] = part;
    }
    __syncthreads();
    if (tid == 0) {
        if (j < i0)
            scores[(b * NCHUNK + i0) * NCHUNK + j] = (float)(sred[0] + sred[1]);
        scores[(b * NCHUNK + i1) * NCHUNK + j] = (float)(sred[2] + sred[3]);
    }
}

// ---------------------------------------------------------------------------
// Stage C: top-7 selection + weights (tiny, serial) — unchanged
// ---------------------------------------------------------------------------
__global__ void topk_kernel(const float* __restrict__ scores,
                            int* __restrict__ ext_idx,
                            float* __restrict__ ext_w) {
    int tid = threadIdx.x;
    if (tid >= NBATCH * NCHUNK) return;
    int b = tid >> 6, i = tid & 63;
    const float* srow = scores + (b * NCHUNK + i) * NCHUNK;

    int nsel = i < KSEL ? i : KSEL;
    float vals[KSEL];
    int   idxs[KSEL];
    unsigned long long used = 0ull;
    for (int s = 0; s < nsel; ++s) {
        float best = -3.0e38f;
        int   bj = 0;
        for (int jj = 0; jj < i; ++jj) {
            if ((used >> jj) & 1ull) continue;
            float v = srow[jj];
            if (v > best) { best = v; bj = jj; }
        }
        used |= 1ull << bj;
        vals[s] = best;
        idxs[s] = bj;
    }
    float vmin = (nsel > 0) ? vals[nsel - 1] : 0.0f;
    float inv  = 1.0f / (vmin + 1e-6f);
    int shift  = KSEL - nsel;
    for (int s = 0; s < KSEL; ++s) {
        int t = s - shift;
        int o = (b * NCHUNK + i) * KSEL + s;
        if (t >= 0) { ext_idx[o] = idxs[t]; ext_w[o] = vals[t] * inv; }
        else        { ext_idx[o] = -1;      ext_w[o] = 0.0f; }
    }
}

// ---------------------------------------------------------------------------
// Stage D: out = dp @ ext + chunk, split-bf16 MFMA, per-slot partials.
// (round-5 version, unchanged)
// ---------------------------------------------------------------------------
__global__ __launch_bounds__(256) void out_mfma(const float* __restrict__ x,
                                                const short* __restrict__ dph,
                                                const short* __restrict__ dpl,
                                                const short* __restrict__ xth,
                                                const short* __restrict__ xtl,
                                                const int* __restrict__ ext_idx,
                                                const float* __restrict__ ext_w,
                                                float* __restrict__ out) {
    __shared__ short As[2][2][128 * 32];  // [buf][h/l][c][k]  32 KB
    __shared__ short Bs[2][2][64 * 32];   // [buf][h/l][e][k]  16 KB
    __shared__ int   sjj[8];
    __shared__ float sww[8];
    __shared__ int   slist[8], sslot[8], snum;
    __shared__ float swei[8];

    const int eq = blockIdx.x, n = blockIdx.y, b = blockIdx.z;
    const int e0 = eq * 64;
    const int tid  = threadIdx.x;
    const int w    = tid >> 6, lane = tid & 63;
    const int wr   = w >> 1, wc = w & 1;
    const int quad = lane >> 4, l15 = lane & 15;
    const int rr   = lane >> 2;
    const int c16  = (lane & 3) * 8;

    if (tid < KSEL) {
        sjj[tid] = ext_idx[(b * NCHUNK + n) * KSEL + tid];
        sww[tid] = ext_w [(b * NCHUNK + n) * KSEL + tid];
    }
    if (tid == KSEL) { sjj[KSEL] = n; sww[KSEL] = 1.0f; }
    __syncthreads();
    if (tid == 0) {
        int c = 0;
        for (int s = 0; s < 8; ++s)
            if (sjj[s] >= 0) { slist[c] = sjj[s]; sslot[c] = s; swei[c] = sww[s]; ++c; }
        snum = c;
    }
    __syncthreads();
    const int NS = snum * 4;   // flattened steps (kk=0..3 per valid slot)

    const short* adp = (w == 1) ? dpl : dph;   // wave 0 -> A hi, wave 1 -> A lo
    const short* bxt = (w == 3) ? xtl : xth;   // wave 2 -> B hi, wave 3 -> B lo

    floatx4 accT[4][2], accP[4][2];
#pragma unroll
    for (int rt = 0; rt < 4; ++rt)
#pragma unroll
        for (int ct = 0; ct < 2; ++ct) accT[rt][ct] = (floatx4){0.f, 0.f, 0.f, 0.f};

    auto stage = [&](int st, int bf) {
        int sv = st >> 2, kk = st & 3;
        if (w < 2) {   // A: dp[c][slot*128 + kk*32 .. +32], 128 rows
            const short* gsrc = adp + (size_t)(sslot[sv] * 128 + kk * 32) + c16;
            short* dst = &As[bf][w][0];
#pragma unroll
            for (int t = 0; t < 8; ++t)
                gl_lds16(gsrc + (size_t)(16 * t + rr) * LEXT, dst + t * 512);
        } else {       // B: xt[e0+e][jj*128 + kk*32 .. +32], 64 rows
            const short* gsrc = bxt + ((size_t)(b * EDIM + e0)) * TLEN
                                + (size_t)(slist[sv] * CS + kk * 32) + c16;
            short* dst = &Bs[bf][w - 2][0];
#pragma unroll
            for (int t = 0; t < 4; ++t)
                gl_lds16(gsrc + (size_t)(16 * t + rr) * TLEN, dst + t * 512);
        }
    };

    stage(0, 0);
    __syncthreads();

    int buf = 0;
    for (int st = 0; st < NS; ++st) {
        if (st + 1 < NS) stage(st + 1, buf ^ 1);

        if ((st & 3) == 0) {
#pragma unroll
            for (int rt = 0; rt < 4; ++rt)
#pragma unroll
                for (int ct = 0; ct < 2; ++ct) accP[rt][ct] = (floatx4){0.f, 0.f, 0.f, 0.f};
        }

        short8 bh[2], bl[2];
#pragma unroll
        for (int ct = 0; ct < 2; ++ct) {
            int e = wc * 32 + ct * 16 + l15;
            bh[ct] = *(const short8*)&Bs[buf][0][e * 32 + quad * 8];
            bl[ct] = *(const short8*)&Bs[buf][1][e * 32 + quad * 8];
        }
#pragma unroll
        for (int rt = 0; rt < 4; ++rt) {
            int r = wr * 64 + rt * 16 + l15;
            short8 ah = *(const short8*)&As[buf][0][r * 32 + quad * 8];
            short8 al = *(const short8*)&As[buf][1][r * 32 + quad * 8];
#pragma unroll
            for (int ct = 0; ct < 2; ++ct) {
                accP[rt][ct] = __builtin_amdgcn_mfma_f32_16x16x32_bf16(ah, bh[ct], accP[rt][ct], 0, 0, 0);
                accP[rt][ct] = __builtin_amdgcn_mfma_f32_16x16x32_bf16(ah, bl[ct], accP[rt][ct], 0, 0, 0);
                accP[rt][ct] = __builtin_amdgcn_mfma_f32_16x16x32_bf16(al, bh[ct], accP[rt][ct], 0, 0, 0);
            }
        }

        if ((st & 3) == 3) {
            float wcur = swei[st >> 2];
#pragma unroll
            for (int rt = 0; rt < 4; ++rt)
#pragma unroll
                for (int ct = 0; ct < 2; ++ct)
#pragma unroll
                    for (int reg = 0; reg < 4; ++reg)
                        accT[rt][ct][reg] += wcur * accP[rt][ct][reg];
        }
        __syncthreads();
        buf ^= 1;
    }

#pragma unroll
    for (int rt = 0; rt < 4; ++rt)
#pragma unroll
        for (int ct = 0; ct < 2; ++ct) {
#pragma unroll
            for (int reg = 0; reg < 4; ++reg) {
                int row = wr * 64 + rt * 16 + quad * 4 + reg;
                int col = wc * 32 + ct * 16 + l15;
                size_t o = ((size_t)(b * TLEN + n * CS + row)) * EDIM + e0 + col;
                out[o] = accT[rt][ct][reg] + x[o];
            }
        }
}

// ---------------------------------------------------------------------------
extern "C" void kernel_launch(void* const* d_in, const int* in_sizes, int n_in,
                              void* d_out, int out_size, void* d_ws, size_t ws_size,
                              hipStream_t stream) {
    const float* x  = (const float*)d_in[0];   // [2, 8192, 256] fp32
    const float* dp = (const float*)d_in[1];   // [128, 1024] fp32
    float* out = (float*)d_out;

    char* ws = (char*)d_ws;
    short* cn_hi  = (short*)(ws);                       // 8 MB
    short* cn_lo  = (short*)(ws + (8u << 20));          // 8 MB
    short* xt_hi  = (short*)(ws + (16u << 20));         // 8 MB
    short* xt_lo  = (short*)(ws + (24u << 20));         // 8 MB
    short* dp_hi  = (short*)(ws + (32u << 20));         // 256 KB
    short* dp_lo  = (short*)(ws + (32u << 20) + 262144);
    float* scores = (float*)(ws + (33u << 20));         // 32 KB
    int*   ext_idx = (int*)  (ws + (33u << 20) + 32768);
    float* ext_w   = (float*)(ws + (33u << 20) + 32768 + 4096);

    normsplit_kernel<<<dim3(NBATCH * TLEN / 4), 256, 0, stream>>>(x, cn_hi, cn_lo);
    xt_split_kernel <<<dim3(EDIM / 64, TLEN / 64, NBATCH), 256, 0, stream>>>(x, xt_hi, xt_lo);
    dp_split_kernel <<<dim3(CS * LEXT / 1024), 256, 0, stream>>>(dp, dp_hi, dp_lo);
    scores_mfma     <<<dim3(32 * 32, NBATCH), 512, 0, stream>>>(cn_hi, cn_lo, scores);
    topk_kernel     <<<1, 128, 0, stream>>>(scores, ext_idx, ext_w);
    out_mfma        <<<dim3(4, NCHUNK, NBATCH), 256, 0, stream>>>(x, dp_hi, dp_lo, xt_hi, xt_lo,
                                                                  ext_idx, ext_w, out);
}

// Round 7
// 271.852 us; speedup vs baseline: 1.2511x; 1.2511x over previous
//
#include <hip/hip_runtime.h>
#include <hip/hip_bf16.h>

// Problem constants (fixed by the reference)
#define CS     128
#define EDIM   256
#define NBATCH 2
#define TLEN   8192
#define NCHUNK 64
#define LEXT   1024
#define KSEL   7

typedef __attribute__((ext_vector_type(8))) short   short8;   // 8 bf16 = 4 VGPR (MFMA A/B frag)
typedef __attribute__((ext_vector_type(4))) float   floatx4;  // MFMA C/D frag

__device__ inline short bf16_of(float f) {
    __hip_bfloat16 h = __float2bfloat16(f);
    return *(short*)&h;
}
__device__ inline float f_of_bf16(short s) {
    __hip_bfloat16 h = *(__hip_bfloat16*)&s;
    return __bfloat162float(h);
}

// async global->LDS, 16B per lane; LDS dest = wave-uniform base + lane*16
__device__ inline void gl_lds16(const void* g, void* l) {
    __builtin_amdgcn_global_load_lds(
        (const __attribute__((address_space(1))) unsigned int*)g,
        (__attribute__((address_space(3))) unsigned int*)l, 16, 0, 0);
}

// ---------------------------------------------------------------------------
// Stage A1: normalize rows, split to bf16 hi/lo (for scores). One wave/row.
// ---------------------------------------------------------------------------
__global__ __launch_bounds__(256) void normsplit_kernel(const float* __restrict__ x,
                                                        short* __restrict__ cn_hi,
                                                        short* __restrict__ cn_lo) {
    int row  = blockIdx.x * 4 + (threadIdx.x >> 6);
    int lane = threadIdx.x & 63;
    const float4 v = ((const float4*)(x + (size_t)row * EDIM))[lane];
    float s = v.x * v.x + v.y * v.y + v.z * v.z + v.w * v.w;
#pragma unroll
    for (int off = 1; off < 64; off <<= 1) s += __shfl_xor(s, off);
    float r = 1.0f / (sqrtf(s) + 1e-6f);

    float c[4] = {v.x * r, v.y * r, v.z * r, v.w * r};
    short hs[4], ls[4];
#pragma unroll
    for (int q = 0; q < 4; ++q) {
        hs[q] = bf16_of(c[q]);
        ls[q] = bf16_of(c[q] - f_of_bf16(hs[q]));
    }
    size_t o = (size_t)row * EDIM + lane * 4;
    *(short4*)(cn_hi + o) = make_short4(hs[0], hs[1], hs[2], hs[3]);
    *(short4*)(cn_lo + o) = make_short4(ls[0], ls[1], ls[2], ls[3]);
}

// ---------------------------------------------------------------------------
// Stage A2: down_proj -> bf16 (single-pass: out GEMM needs hi only)
// ---------------------------------------------------------------------------
__global__ __launch_bounds__(256) void dp_split_kernel(const float* __restrict__ dp,
                                                       short* __restrict__ dph) {
    int idx = (blockIdx.x * 256 + threadIdx.x) * 4;
    float4 v = *(const float4*)(dp + idx);
    *(short4*)(dph + idx) = make_short4(bf16_of(v.x), bf16_of(v.y), bf16_of(v.z), bf16_of(v.w));
}

// ---------------------------------------------------------------------------
// Stage A3: transpose x to [b][e][t], bf16 (hi only, for out B-operand)
// ---------------------------------------------------------------------------
__global__ __launch_bounds__(256) void xt_split_kernel(const float* __restrict__ x,
                                                       short* __restrict__ xth) {
    __shared__ float tile[64][68];
    const int e0 = blockIdx.x * 64, t0 = blockIdx.y * 64, b = blockIdx.z;
    const int tid = threadIdx.x;
    const int cr = tid >> 4, cc = (tid & 15) * 4;
#pragma unroll
    for (int p = 0; p < 4; ++p) {
        int r = cr + p * 16;
        float4 v = *(const float4*)(x + ((size_t)(b * TLEN + t0 + r)) * EDIM + e0 + cc);
        *(float4*)&tile[r][cc] = v;
    }
    __syncthreads();
    const int e = tid >> 2, toff = (tid & 3) * 16;
    short hs[16];
#pragma unroll
    for (int q = 0; q < 16; ++q) hs[q] = bf16_of(tile[toff + q][e]);
    size_t o = ((size_t)(b * EDIM + e0 + e)) * TLEN + t0 + toff;
#pragma unroll
    for (int q4 = 0; q4 < 4; ++q4)
        *(short4*)(xth + o + q4 * 4) = make_short4(hs[q4*4], hs[q4*4+1], hs[q4*4+2], hs[q4*4+3]);
}

// ---------------------------------------------------------------------------
// Stage B: split-bf16 MFMA cosine-sim GEMM + rowmax + sum -> scores[b,i,j]
// (exact round-3 version — best measured: 128 µs, MfmaUtil 34.5%)
// ---------------------------------------------------------------------------
__global__ __launch_bounds__(256) void scores_mfma(const short* __restrict__ cn_hi,
                                                   const short* __restrict__ cn_lo,
                                                   float* __restrict__ scores) {
    __shared__ short  tiles[4][128 * 32];   // 32 KB
    __shared__ float  redbuf[2][128];
    __shared__ double red2[2];

    const int p = blockIdx.x, b = blockIdx.y;
    int i = (int)((1.0f + sqrtf(1.0f + 8.0f * (float)p)) * 0.5f);
    while (i * (i - 1) / 2 > p) --i;
    while (i * (i + 1) / 2 <= p) ++i;
    const int j = p - i * (i - 1) / 2;

    const int tid  = threadIdx.x;
    const int w    = tid >> 6, lane = tid & 63;
    const int wr   = w >> 1, wc = w & 1;
    const int quad = lane >> 4, l15 = lane & 15;

    const short* sarr  = (w & 1) ? cn_lo : cn_hi;
    const size_t sbase = ((size_t)b * TLEN + ((w >> 1) ? j : i) * CS) * EDIM;
    const int rr  = lane >> 2;
    const int c16 = (lane & 3) * 8;

    floatx4 acc[4][4];
#pragma unroll
    for (int rt = 0; rt < 4; ++rt)
#pragma unroll
        for (int ct = 0; ct < 4; ++ct) acc[rt][ct] = (floatx4){0.f, 0.f, 0.f, 0.f};

    for (int ks = 0; ks < 8; ++ks) {
        const short* gsrc = sarr + sbase + ks * 32 + c16;
        short* ldst = &tiles[w][0];
#pragma unroll
        for (int t = 0; t < 8; ++t)
            gl_lds16(gsrc + (size_t)(16 * t + rr) * EDIM, ldst + t * 512);
        __syncthreads();

        short8 bh[4], bl[4];
#pragma unroll
        for (int ct = 0; ct < 4; ++ct) {
            int r = wc * 64 + ct * 16 + l15;
            bh[ct] = *(const short8*)&tiles[2][r * 32 + quad * 8];
            bl[ct] = *(const short8*)&tiles[3][r * 32 + quad * 8];
        }
#pragma unroll
        for (int rt = 0; rt < 4; ++rt) {
            int r = wr * 64 + rt * 16 + l15;
            short8 ah = *(const short8*)&tiles[0][r * 32 + quad * 8];
            short8 al = *(const short8*)&tiles[1][r * 32 + quad * 8];
#pragma unroll
            for (int ct = 0; ct < 4; ++ct) {
                acc[rt][ct] = __builtin_amdgcn_mfma_f32_16x16x32_bf16(ah, bh[ct], acc[rt][ct], 0, 0, 0);
                acc[rt][ct] = __builtin_amdgcn_mfma_f32_16x16x32_bf16(ah, bl[ct], acc[rt][ct], 0, 0, 0);
                acc[rt][ct] = __builtin_amdgcn_mfma_f32_16x16x32_bf16(al, bh[ct], acc[rt][ct], 0, 0, 0);
            }
        }
        __syncthreads();
    }

#pragma unroll
    for (int rt = 0; rt < 4; ++rt) {
        float m[4];
#pragma unroll
        for (int reg = 0; reg < 4; ++reg) {
            float mm = acc[rt][0][reg];
#pragma unroll
            for (int ct = 1; ct < 4; ++ct) mm = fmaxf(mm, acc[rt][ct][reg]);
            m[reg] = mm;
        }
#pragma unroll
        for (int off = 1; off < 16; off <<= 1)
#pragma unroll
            for (int reg = 0; reg < 4; ++reg) m[reg] = fmaxf(m[reg], __shfl_xor(m[reg], off));
        if (l15 == 0) {
#pragma unroll
            for (int reg = 0; reg < 4; ++reg)
                redbuf[wc][wr * 64 + rt * 16 + quad * 4 + reg] = m[reg];
        }
    }
    __syncthreads();

    double part = 0.0;
    if (tid < 128) part = (double)fmaxf(redbuf[0][tid], redbuf[1][tid]);
#pragma unroll
    for (int off = 1; off < 64; off <<= 1) part += __shfl_xor(part, off);
    if (lane == 0 && w < 2) red2[w] = part;
    __syncthreads();
    if (tid == 0) scores[(b * NCHUNK + i) * NCHUNK + j] = (float)(red2[0] + red2[1]);
}

// ---------------------------------------------------------------------------
// Stage C: top-7 selection + weights (tiny, serial) — unchanged
// ---------------------------------------------------------------------------
__global__ void topk_kernel(const float* __restrict__ scores,
                            int* __restrict__ ext_idx,
                            float* __restrict__ ext_w) {
    int tid = threadIdx.x;
    if (tid >= NBATCH * NCHUNK) return;
    int b = tid >> 6, i = tid & 63;
    const float* srow = scores + (b * NCHUNK + i) * NCHUNK;

    int nsel = i < KSEL ? i : KSEL;
    float vals[KSEL];
    int   idxs[KSEL];
    unsigned long long used = 0ull;
    for (int s = 0; s < nsel; ++s) {
        float best = -3.0e38f;
        int   bj = 0;
        for (int jj = 0; jj < i; ++jj) {
            if ((used >> jj) & 1ull) continue;
            float v = srow[jj];
            if (v > best) { best = v; bj = jj; }
        }
        used |= 1ull << bj;
        vals[s] = best;
        idxs[s] = bj;
    }
    float vmin = (nsel > 0) ? vals[nsel - 1] : 0.0f;
    float inv  = 1.0f / (vmin + 1e-6f);
    int shift  = KSEL - nsel;
    for (int s = 0; s < KSEL; ++s) {
        int t = s - shift;
        int o = (b * NCHUNK + i) * KSEL + s;
        if (t >= 0) { ext_idx[o] = idxs[t]; ext_w[o] = vals[t] * inv; }
        else        { ext_idx[o] = -1;      ext_w[o] = 0.0f; }
    }
}

// ---------------------------------------------------------------------------
// Stage D v3: out = dp @ ext + chunk, SINGLE-PASS bf16 MFMA (no hi/lo —
// out has no selection sensitivity; error budget analysis in journal),
// full 128-e tile -> grid (2,64,2)=256 blocks, dp read once per block.
// Per-slot partials: accT += w_s * (dp_s @ chunk_jj), flattened (slot,kk)
// steps, double-buffered LDS (2x8KB A + 2x8KB B), one barrier per step.
// ---------------------------------------------------------------------------
__global__ __launch_bounds__(256) void out_mfma(const float* __restrict__ x,
                                                const short* __restrict__ dph,
                                                const short* __restrict__ xth,
                                                const int* __restrict__ ext_idx,
                                                const float* __restrict__ ext_w,
                                                float* __restrict__ out) {
    __shared__ short As[2][128 * 32];   // [buf][c][k]  8 KB each
    __shared__ short Bs[2][128 * 32];   // [buf][e][k]  8 KB each
    __shared__ int   sjj[8];
    __shared__ float sww[8];
    __shared__ int   slist[8], sslot[8], snum;
    __shared__ float swei[8];

    const int eq = blockIdx.x, n = blockIdx.y, b = blockIdx.z;
    const int e0 = eq * 128;
    const int tid  = threadIdx.x;
    const int w    = tid >> 6, lane = tid & 63;
    const int wr   = w >> 1, wc = w & 1;
    const int quad = lane >> 4, l15 = lane & 15;
    const int rr   = lane >> 2;
    const int c16  = (lane & 3) * 8;

    if (tid < KSEL) {
        sjj[tid] = ext_idx[(b * NCHUNK + n) * KSEL + tid];
        sww[tid] = ext_w [(b * NCHUNK + n) * KSEL + tid];
    }
    if (tid == KSEL) { sjj[KSEL] = n; sww[KSEL] = 1.0f; }
    __syncthreads();
    if (tid == 0) {
        int c = 0;
        for (int s = 0; s < 8; ++s)
            if (sjj[s] >= 0) { slist[c] = sjj[s]; sslot[c] = s; swei[c] = sww[s]; ++c; }
        snum = c;
    }
    __syncthreads();
    const int NS = snum * 4;   // flattened steps (kk=0..3 per valid slot)

    // staging: waves 0,1 -> A rows w*64..+63 (dp); waves 2,3 -> B rows (w-2)*64..+63 (xT)
    auto stage = [&](int st, int bf) {
        int sv = st >> 2, kk = st & 3;
        if (w < 2) {
            const short* gsrc = dph + (size_t)(sslot[sv] * 128 + kk * 32) + c16;
#pragma unroll
            for (int t = 0; t < 4; ++t)
                gl_lds16(gsrc + (size_t)(w * 64 + t * 16 + rr) * LEXT,
                         &As[bf][(w * 64 + t * 16) * 32]);
        } else {
            const short* gsrc = xth + ((size_t)(b * EDIM + e0)) * TLEN
                                + (size_t)(slist[sv] * CS + kk * 32) + c16;
#pragma unroll
            for (int t = 0; t < 4; ++t)
                gl_lds16(gsrc + (size_t)((w - 2) * 64 + t * 16 + rr) * TLEN,
                         &Bs[bf][((w - 2) * 64 + t * 16) * 32]);
        }
    };

    floatx4 accT[4][4], accP[4][4];
#pragma unroll
    for (int rt = 0; rt < 4; ++rt)
#pragma unroll
        for (int ct = 0; ct < 4; ++ct) accT[rt][ct] = (floatx4){0.f, 0.f, 0.f, 0.f};

    stage(0, 0);
    __syncthreads();

    int buf = 0;
    for (int st = 0; st < NS; ++st) {
        if (st + 1 < NS) stage(st + 1, buf ^ 1);

        if ((st & 3) == 0) {
#pragma unroll
            for (int rt = 0; rt < 4; ++rt)
#pragma unroll
                for (int ct = 0; ct < 4; ++ct) accP[rt][ct] = (floatx4){0.f, 0.f, 0.f, 0.f};
        }

        short8 bh[4];
#pragma unroll
        for (int ct = 0; ct < 4; ++ct) {
            int e = wc * 64 + ct * 16 + l15;
            bh[ct] = *(const short8*)&Bs[buf][e * 32 + quad * 8];
        }
#pragma unroll
        for (int rt = 0; rt < 4; ++rt) {
            int r = wr * 64 + rt * 16 + l15;
            short8 ah = *(const short8*)&As[buf][r * 32 + quad * 8];
#pragma unroll
            for (int ct = 0; ct < 4; ++ct)
                accP[rt][ct] = __builtin_amdgcn_mfma_f32_16x16x32_bf16(ah, bh[ct], accP[rt][ct], 0, 0, 0);
        }

        if ((st & 3) == 3) {
            float wcur = swei[st >> 2];
#pragma unroll
            for (int rt = 0; rt < 4; ++rt)
#pragma unroll
                for (int ct = 0; ct < 4; ++ct)
#pragma unroll
                    for (int reg = 0; reg < 4; ++reg)
                        accT[rt][ct][reg] += wcur * accP[rt][ct][reg];
        }
        __syncthreads();
        buf ^= 1;
    }

    // epilogue: D[row = wr*64+rt*16+quad*4+reg][col = wc*64+ct*16+l15] + chunk
#pragma unroll
    for (int rt = 0; rt < 4; ++rt)
#pragma unroll
        for (int ct = 0; ct < 4; ++ct) {
#pragma unroll
            for (int reg = 0; reg < 4; ++reg) {
                int row = wr * 64 + rt * 16 + quad * 4 + reg;
                int col = wc * 64 + ct * 16 + l15;
                size_t o = ((size_t)(b * TLEN + n * CS + row)) * EDIM + e0 + col;
                out[o] = accT[rt][ct][reg] + x[o];
            }
        }
}

// ---------------------------------------------------------------------------
extern "C" void kernel_launch(void* const* d_in, const int* in_sizes, int n_in,
                              void* d_out, int out_size, void* d_ws, size_t ws_size,
                              hipStream_t stream) {
    const float* x  = (const float*)d_in[0];   // [2, 8192, 256] fp32
    const float* dp = (const float*)d_in[1];   // [128, 1024] fp32
    float* out = (float*)d_out;

    char* ws = (char*)d_ws;
    short* cn_hi  = (short*)(ws);                       // 8 MB
    short* cn_lo  = (short*)(ws + (8u << 20));          // 8 MB
    short* xt_hi  = (short*)(ws + (16u << 20));         // 8 MB
    short* dp_hi  = (short*)(ws + (24u << 20));         // 256 KB
    float* scores = (float*)(ws + (25u << 20));         // 32 KB
    int*   ext_idx = (int*)  (ws + (25u << 20) + 32768);
    float* ext_w   = (float*)(ws + (25u << 20) + 32768 + 4096);

    normsplit_kernel<<<dim3(NBATCH * TLEN / 4), 256, 0, stream>>>(x, cn_hi, cn_lo);
    xt_split_kernel <<<dim3(EDIM / 64, TLEN / 64, NBATCH), 256, 0, stream>>>(x, xt_hi);
    dp_split_kernel <<<dim3(CS * LEXT / 1024), 256, 0, stream>>>(dp, dp_hi);
    scores_mfma     <<<dim3(NCHUNK * (NCHUNK - 1) / 2, NBATCH), 256, 0, stream>>>(cn_hi, cn_lo, scores);
    topk_kernel     <<<1, 128, 0, stream>>>(scores, ext_idx, ext_w);
    out_mfma        <<<dim3(2, NCHUNK, NBATCH), 256, 0, stream>>>(x, dp_hi, xt_hi,
                                                                  ext_idx, ext_w, out);
}